// Round 9
// baseline (799.560 us; speedup 1.0000x reference)
//
#include <hip/hip_runtime.h>
#include <hip/hip_bf16.h>

// ELMo 2-layer biLSTM, B=64 T=256 U=256. Persistent RNN, data-tagged sync.
//  R9 = R6 (798us, known-good) + s_sleep backoff in the UNCHANGED full-window
//  poll loop. No other deltas (R7/R8 timed out on one pod handle; suspect
//  R7 ws-overflow wedged the queue -> re-establish known-good structure).
//  - 128 WGs = 8 clusters (4 rowgroups x 2 dirs) x 16 slices; cluster=blk&7.
//  - 512 thr = 8 waves (gate g x K-half kh); weights bf16 in LDS (128KB).
//  - h exchange: u32 (tag<<16)|bf16 relaxed sc1 stores, fire-and-forget;
//    consumers poll their full 32B(+32B) window, verify ALL 16 tags.
//  - 2-deep parity ring race-free: a word reaches tag t+2 only after every
//    WG (incl. this consumer) consumed tag t.

#define TT 256
#define TM 255
#define NU 256
#define NG 1024
#define BB 64

typedef __attribute__((ext_vector_type(8))) short short8;
typedef __attribute__((ext_vector_type(4))) float f32x4;
typedef __attribute__((ext_vector_type(4))) unsigned int u32x4;

__device__ __forceinline__ unsigned short f2bf(float v) {
  unsigned int x = __float_as_uint(v);
  return (unsigned short)((x + 0x7FFFu + ((x >> 16) & 1u)) >> 16);
}
__device__ __forceinline__ float sigm(float x) { return 1.f / (1.f + __expf(-x)); }
__device__ __forceinline__ float tanhp(float x) {
  x = fminf(fmaxf(x, -15.f), 15.f);
  float e = __expf(-2.f * x);
  return (1.f - e) / (1.f + e);
}
__device__ __forceinline__ u32x4 llc_load16(const unsigned int* p) {
  u32x4 r;
  asm volatile("global_load_dwordx4 %0, %1, off sc0 sc1" : "=v"(r) : "v"(p));
  return r;
}
#define VMCNT0() asm volatile("s_waitcnt vmcnt(0)" ::: "memory")
#define LGKM0() asm volatile("s_waitcnt lgkmcnt(0)" ::: "memory")
#define SCHEDBAR() __builtin_amdgcn_sched_barrier(0)
#define BAR() __builtin_amdgcn_s_barrier()

__global__ void embed_kernel(const int* __restrict__ seqs, const float* __restrict__ E,
                             unsigned short* __restrict__ embb, float* __restrict__ out) {
  int b = blockIdx.x, t = blockIdx.y, d = threadIdx.x;
  int s = seqs[b * TT + t];
  float v = E[(size_t)s * NU + d];
  embb[((size_t)(b * TT + t)) * NU + d] = f2bf(v);
  if (t < TM) out[(((size_t)(0 * BB + b)) * TM + t) * NU + d] = v;
  if (t >= 1) out[(((size_t)(3 * BB + b)) * TM + (t - 1)) * NU + d] = v;
}

__launch_bounds__(512, 1)
__global__ void lstm_kernel(const int* __restrict__ seqs,
                            const float* __restrict__ Wf, const float* __restrict__ Uf,
                            const float* __restrict__ bf,
                            const float* __restrict__ Wb, const float* __restrict__ Ub,
                            const float* __restrict__ bb,
                            const unsigned short* __restrict__ embb,
                            unsigned int* __restrict__ Hbuf, float* __restrict__ out) {
  extern __shared__ char smem[];
  unsigned short* wlds = (unsigned short*)smem;   // 128KB weights
  float* zpart = (float*)(smem + 131072);         // [2][4][2][16][16] f32 = 16KB
  char* hlb0 = smem + 147456;                     // 8KB swizzled h0 tile (bf16)
  char* hlb1 = smem + 155648;                     // 8KB swizzled h1 tile

  const int tid = threadIdx.x;
  const int blk = blockIdx.x;
  const int cluster = blk & 7, slice = blk >> 3;  // cluster -> same XCD (perf only)
  const int dir = cluster >> 2, rg = cluster & 3;
  const int ubase = slice << 4;
  const int wave = tid >> 6, g = wave & 3, kh = wave >> 2;
  const int lane = tid & 63, q = lane >> 4, n15 = lane & 15;
  const int tlay = tid >> 8, ct = tid & 255, crow = ct >> 4, cn = ct & 15;
  const int brow = rg * 16 + crow;

  const float* W0 = dir ? Wb : Wf;
  const float* U0 = dir ? Ub : Uf;
  const float* b0p = dir ? bb : bf;
  const float* mats[4] = {W0, U0, W0 + NU * NG, U0 + NU * NG};

  // ---- weights -> LDS (bf16 B-frag layout; k=kb*32+q*8+j within kh-half)
  {
    int c = tid & 63;
    int gg = c >> 4, n = c & 15;
    int col = (gg << 8) + ubase + n;
    int koff = tid >> 6;
    for (int m = 0; m < 4; m++) {
      const float* S = mats[m];
      unsigned short* WL = wlds + m * 16384;
      for (int k0 = 0; k0 < 256; k0 += 8) {
        int k = k0 + koff;
        int li = (gg << 12) + ((k >> 5) << 9) + (((k >> 3) & 3) << 7) + (n << 3) + (k & 7);
        WL[li] = f2bf(S[(size_t)k * NG + col]);
      }
    }
  }

  float bi[4];
  {
    const float* bp = tlay ? (b0p + NG) : b0p;
    #pragma unroll
    for (int gg = 0; gg < 4; gg++) bi[gg] = bp[(gg << 8) + ubase + cn];
  }
  float cst = 0.f, hv = 0.f;

  __syncthreads();

  const unsigned short* wb0 = wlds + (g << 12) + (kh << 11) + (q << 7) + (n15 << 3);
  const unsigned short* ub0 = wb0 + 16384;
  const unsigned short* wb1 = wb0 + 32768;
  const unsigned short* ub1 = wb0 + 49152;
  const int wsw = (tid * 16) ^ (((tid >> 5) & 7) << 4);
  const int fb = n15 * 512 + kh * 256;
  const int fx = (n15 & 7) << 4;
  const int zwr = (g << 9) + (kh << 8) + n15;

  // ring word slot: [lay][parity][cluster][4096]; parity stride 32768 words
  unsigned int* hst = Hbuf + ((size_t)(tlay * 2 * 8 + cluster)) * 4096 + crow * 256 + ubase + cn;

  // ================= tick 0: emb-only, L0 combine =================
  {
    int tx = dir ? TM : 0;
    const unsigned short* ep =
        embb + ((size_t)((rg * 16 + n15) * TT + tx)) * NU + kh * 128 + q * 8;
    f32x4 acc0 = {0.f, 0.f, 0.f, 0.f};
    #pragma unroll
    for (int kb = 0; kb < 4; kb++) {
      short8 a = *(const short8*)(ep + kb * 32);
      short8 b = *(const short8*)(wb0 + (kb << 9));
      acc0 = __builtin_amdgcn_mfma_f32_16x16x32_bf16(a, b, acc0, 0, 0, 0);
    }
    #pragma unroll
    for (int j = 0; j < 4; j++) zpart[zwr + (((q << 2) + j) << 4)] = acc0[j];
    LGKM0(); SCHEDBAR(); BAR();
    if (tlay == 0) {
      float z[4];
      #pragma unroll
      for (int gg = 0; gg < 4; gg++)
        z[gg] = zpart[(gg * 2) * 256 + crow * 16 + cn] +
                zpart[(gg * 2 + 1) * 256 + crow * 16 + cn] + bi[gg];
      float cnw = sigm(z[1]) * cst + sigm(z[0]) * tanhp(z[2]);
      float hnw = sigm(z[3]) * tanhp(cnw);
      int traw = dir ? TM : 0;
      if (seqs[brow * TT + traw] != 0) { cst = cnw; hv = hnw; }
      __hip_atomic_store(hst, (1u << 16) | (unsigned)f2bf(hv),
                         __ATOMIC_RELAXED, __HIP_MEMORY_SCOPE_AGENT);
      int tout = dir ? TM - 1 : 0;
      out[(((size_t)((1 + dir * 3) * BB + brow)) * TM + tout) * NU + ubase + cn] = hv;
    }
  }

  // ================= ticks 1..255 =================
  for (int tau = 1; tau < 256; ++tau) {
    const bool doL0 = (tau < TM);
    const bool doH1 = (tau >= 2);
    const int step = tlay ? tau - 1 : tau;

    int mval = 0;
    if (tlay ? true : doL0) mval = seqs[brow * TT + (dir ? TM - step : step)];

    // emb frag loads (L2-cached; in flight during poll)
    short8 ea[4];
    if (doL0) {
      int tx = dir ? (TM - tau) : tau;
      const unsigned short* ep =
          embb + ((size_t)((rg * 16 + n15) * TT + tx)) * NU + kh * 128 + q * 8;
      #pragma unroll
      for (int kb = 0; kb < 4; kb++) ea[kb] = *(const short8*)(ep + kb * 32);
    }

    // ---- poll tagged h words (full 32B(+32B) window, ALL tags verified)
    const unsigned tg = (unsigned)tau;
    const int p = (tau + 1) & 1;  // parity of producing tick tau-1
    const unsigned int* c0 = Hbuf + ((size_t)(p * 8 + cluster)) * 4096 + tid * 8;
    const unsigned int* c1 = Hbuf + ((size_t)((2 + p) * 8 + cluster)) * 4096 + tid * 8;
    u32x4 a0 = {0, 0, 0, 0}, a1 = {0, 0, 0, 0}, b0v = {0, 0, 0, 0}, b1v = {0, 0, 0, 0};
    int miss = 0;
    for (;;) {
      a0 = llc_load16(c0);
      a1 = llc_load16(c0 + 4);
      if (doH1) { b0v = llc_load16(c1); b1v = llc_load16(c1 + 4); }
      VMCNT0(); SCHEDBAR();
      bool ok = (a0[0] >> 16) == tg && (a0[1] >> 16) == tg && (a0[2] >> 16) == tg &&
                (a0[3] >> 16) == tg && (a1[0] >> 16) == tg && (a1[1] >> 16) == tg &&
                (a1[2] >> 16) == tg && (a1[3] >> 16) == tg;
      if (doH1)
        ok = ok && (b0v[0] >> 16) == tg && (b0v[1] >> 16) == tg && (b0v[2] >> 16) == tg &&
             (b0v[3] >> 16) == tg && (b1v[0] >> 16) == tg && (b1v[1] >> 16) == tg &&
             (b1v[2] >> 16) == tg && (b1v[3] >> 16) == tg;
      if (__all(ok)) break;
      if (++miss > 2) __builtin_amdgcn_s_sleep(1);  // backoff: cut poll storm
    }
    // strip tags -> packed bf16, stage to swizzled LDS
    u32x4 s0, s1;
    s0[0] = (a0[0] & 0xFFFFu) | (a0[1] << 16);
    s0[1] = (a0[2] & 0xFFFFu) | (a0[3] << 16);
    s0[2] = (a1[0] & 0xFFFFu) | (a1[1] << 16);
    s0[3] = (a1[2] & 0xFFFFu) | (a1[3] << 16);
    *(u32x4*)(hlb0 + wsw) = s0;
    if (doH1) {
      s1[0] = (b0v[0] & 0xFFFFu) | (b0v[1] << 16);
      s1[1] = (b0v[2] & 0xFFFFu) | (b0v[3] << 16);
      s1[2] = (b1v[0] & 0xFFFFu) | (b1v[1] << 16);
      s1[3] = (b1v[2] & 0xFFFFu) | (b1v[3] << 16);
      *(u32x4*)(hlb1 + wsw) = s1;
    }
    LGKM0(); SCHEDBAR(); BAR();

    // ---- MFMAs
    f32x4 acc0 = {0.f, 0.f, 0.f, 0.f}, acc1 = {0.f, 0.f, 0.f, 0.f};
    if (doL0) {
      #pragma unroll
      for (int kb = 0; kb < 4; kb++)
        acc0 = __builtin_amdgcn_mfma_f32_16x16x32_bf16(
            ea[kb], *(const short8*)(wb0 + (kb << 9)), acc0, 0, 0, 0);
    }
    #pragma unroll
    for (int kb = 0; kb < 4; kb++) {
      short8 h0f = *(const short8*)(hlb0 + ((fb + kb * 64 + q * 16) ^ fx));
      if (doL0)
        acc0 = __builtin_amdgcn_mfma_f32_16x16x32_bf16(
            h0f, *(const short8*)(ub0 + (kb << 9)), acc0, 0, 0, 0);
      acc1 = __builtin_amdgcn_mfma_f32_16x16x32_bf16(
          h0f, *(const short8*)(wb1 + (kb << 9)), acc1, 0, 0, 0);
    }
    if (doH1) {
      #pragma unroll
      for (int kb = 0; kb < 4; kb++) {
        short8 h1f = *(const short8*)(hlb1 + ((fb + kb * 64 + q * 16) ^ fx));
        acc1 = __builtin_amdgcn_mfma_f32_16x16x32_bf16(
            h1f, *(const short8*)(ub1 + (kb << 9)), acc1, 0, 0, 0);
      }
    }

    // ---- z partials
    if (doL0) {
      #pragma unroll
      for (int j = 0; j < 4; j++) zpart[zwr + (((q << 2) + j) << 4)] = acc0[j];
    }
    #pragma unroll
    for (int j = 0; j < 4; j++) zpart[2048 + zwr + (((q << 2) + j) << 4)] = acc1[j];
    LGKM0(); SCHEDBAR(); BAR();

    // ---- combine (L0: threads 0-255 @ step tau; L1: threads 256-511 @ tau-1)
    if (tlay ? true : doL0) {
      float z[4];
      #pragma unroll
      for (int gg = 0; gg < 4; gg++)
        z[gg] = zpart[(tlay * 8 + gg * 2) * 256 + crow * 16 + cn] +
                zpart[(tlay * 8 + gg * 2 + 1) * 256 + crow * 16 + cn] + bi[gg];
      float cnw = sigm(z[1]) * cst + sigm(z[0]) * tanhp(z[2]);
      float hnw = sigm(z[3]) * tanhp(cnw);
      if (mval) { cst = cnw; hv = hnw; }
      // ring store: tag tau+1, parity tau&1, fire-and-forget sc1
      __hip_atomic_store(hst + (size_t)(tau & 1) * 32768,
                         ((unsigned)(tau + 1) << 16) | (unsigned)f2bf(hv),
                         __ATOMIC_RELAXED, __HIP_MEMORY_SCOPE_AGENT);
      int tout = dir ? TM - 1 - step : step;
      out[(((size_t)((1 + tlay + dir * 3) * BB + brow)) * TM + tout) * NU + ubase + cn] = hv;
    }
  }
}

extern "C" void kernel_launch(void* const* d_in, const int* in_sizes, int n_in,
                              void* d_out, int out_size, void* d_ws, size_t ws_size,
                              hipStream_t stream) {
  const int* seqs = (const int*)d_in[0];
  const float* E = (const float*)d_in[1];
  const float* Wf = (const float*)d_in[2];
  const float* Uf = (const float*)d_in[3];
  const float* bfp = (const float*)d_in[4];
  const float* Wb = (const float*)d_in[5];
  const float* Ub = (const float*)d_in[6];
  const float* bbp = (const float*)d_in[7];
  float* out = (float*)d_out;

  char* ws = (char*)d_ws;
  unsigned int* Hbuf = (unsigned int*)ws;                 // [2 lay][2 par][8 cl][4096] u32 = 512KB
  unsigned short* embb = (unsigned short*)(ws + 1048576); // 8MB bf16 emb

  hipMemsetAsync(Hbuf, 0, 4 * 8 * 4096 * sizeof(unsigned int), stream);

  hipLaunchKernelGGL(embed_kernel, dim3(BB, TT), dim3(256), 0, stream,
                     seqs, E, embb, out);

  int smem = 163840;  // 128K weights + 16K zpart + 2x8K h tiles
  hipFuncSetAttribute(reinterpret_cast<const void*>(lstm_kernel),
                      hipFuncAttributeMaxDynamicSharedMemorySize, smem);
  hipLaunchKernelGGL(lstm_kernel, dim3(128), dim3(512), smem, stream,
                     seqs, Wf, Uf, bfp, Wb, Ub, bbp, embb, Hbuf, out);
}

// Round 10
// 622.536 us; speedup vs baseline: 1.2844x; 1.2844x over previous
//
#include <hip/hip_runtime.h>
#include <hip/hip_bf16.h>

// ELMo 2-layer biLSTM, B=64 T=256 U=256. Persistent RNN, data-tagged sync.
//  R10 = R9 skeleton + three cuts:
//   1. Weights in VGPRs (wreg[16], R5's proven load pattern) -> 16 fewer
//      ds_read_b128/wave/tick; mask table moves back to LDS (rule #20).
//   2. Deferred out-store: combine saves (addr,val); store issues in the NEXT
//      tick's poll as the YOUNGEST vmem op; poll uses counted VMCNT(1) so the
//      HBM store-ack never blocks. Stale-reg tolerance: a reg only passes the
//      tag check with tag==tau, and any same-address load with tag tau returns
//      identical data (slot's next write is tau+2, gated on our consumption).
//   3. Pre-poll emb MFMA: ea prefetched via asm at tick end (BEFORE ring store
//      so tick-start VMCNT(1) drains exactly ea), x-part MFMAs run pre-poll.
//  All asm loads carry "=&v" (early-clobber): R7/R8 hangs attributed to dest/
//  addr register overlap in re-executed poll loops.
//  Vmem ledger (issue order per tick, all threads uniform):
//   [ea4(prefetch), ringstore1] -> tickstart VMCNT(1) drains ea4.
//   poll iter1: +[ringloads(2|4), outstore1] -> VMCNT(1) drains rs+ringloads.
//   poll iterK: +[ringloads] -> VMCNT(1); youngest may stay stale (tolerated).

#define TT 256
#define TM 255
#define NU 256
#define NG 1024
#define BB 64

typedef __attribute__((ext_vector_type(8))) short short8;
typedef __attribute__((ext_vector_type(4))) float f32x4;
typedef __attribute__((ext_vector_type(4))) unsigned int u32x4;

__device__ __forceinline__ unsigned short f2bf(float v) {
  unsigned int x = __float_as_uint(v);
  return (unsigned short)((x + 0x7FFFu + ((x >> 16) & 1u)) >> 16);
}
__device__ __forceinline__ float sigm(float x) { return 1.f / (1.f + __expf(-x)); }
__device__ __forceinline__ float tanhp(float x) {
  x = fminf(fmaxf(x, -15.f), 15.f);
  float e = __expf(-2.f * x);
  return (1.f - e) / (1.f + e);
}
#define VMCNT(n) asm volatile("s_waitcnt vmcnt(" #n ")" ::: "memory")
#define LGKM0() asm volatile("s_waitcnt lgkmcnt(0)" ::: "memory")
#define SCHEDBAR() __builtin_amdgcn_sched_barrier(0)
#define BAR() __builtin_amdgcn_s_barrier()

// LLC-coherent 16B load; EARLY-CLOBBER dest (never overlap addr pair).
#define LLC_LOAD16(dst, ptr) \
  asm volatile("global_load_dwordx4 %0, %1, off sc0 sc1" : "=&v"(dst) : "v"(ptr) : "memory")
// cached 16B load (emb prefetch), untracked by compiler
#define CACH_LOAD16(dst, ptr) \
  asm volatile("global_load_dwordx4 %0, %1, off" : "=&v"(dst) : "v"(ptr) : "memory")
#define STORE4(ptr, val) \
  asm volatile("global_store_dword %0, %1, off" :: "v"(ptr), "v"(val) : "memory")

__global__ void embed_kernel(const int* __restrict__ seqs, const float* __restrict__ E,
                             unsigned short* __restrict__ embb, float* __restrict__ out) {
  int b = blockIdx.x, t = blockIdx.y, d = threadIdx.x;
  int s = seqs[b * TT + t];
  float v = E[(size_t)s * NU + d];
  embb[((size_t)(b * TT + t)) * NU + d] = f2bf(v);
  if (t < TM) out[(((size_t)(0 * BB + b)) * TM + t) * NU + d] = v;
  if (t >= 1) out[(((size_t)(3 * BB + b)) * TM + (t - 1)) * NU + d] = v;
}

__launch_bounds__(512, 1)
__global__ void lstm_kernel(const int* __restrict__ seqs,
                            const float* __restrict__ Wf, const float* __restrict__ Uf,
                            const float* __restrict__ bf,
                            const float* __restrict__ Wb, const float* __restrict__ Ub,
                            const float* __restrict__ bb,
                            const unsigned short* __restrict__ embb,
                            unsigned int* __restrict__ Hbuf, float* __restrict__ out) {
  extern __shared__ char smem[];
  float* zpart = (float*)smem;                    // [2][4][2][16][16] f32 = 16KB
  char* hlb0 = smem + 16384;                      // 8KB swizzled h0 tile
  char* hlb1 = smem + 24576;                      // 8KB swizzled h1 tile
  unsigned char* mskl = (unsigned char*)(smem + 32768);  // [64][256] = 16KB

  const int tid = threadIdx.x;
  const int blk = blockIdx.x;
  const int cluster = blk & 7, slice = blk >> 3;  // cluster -> same XCD (perf only)
  const int dir = cluster >> 2, rg = cluster & 3;
  const int ubase = slice << 4;
  const int wave = tid >> 6, g = wave & 3, kh = wave >> 2;
  const int lane = tid & 63, q = lane >> 4, n15 = lane & 15;
  const int tlay = tid >> 8, ct = tid & 255, crow = ct >> 4, cn = ct & 15;
  const int brow = rg * 16 + crow;

  const float* W0 = dir ? Wb : Wf;
  const float* U0 = dir ? Ub : Uf;
  const float* b0p = dir ? bb : bf;
  const float* mats[4] = {W0, U0, W0 + NU * NG, U0 + NU * NG};

  // ---- weights -> VGPRs: wreg[m*4+kb][j] = mat[kh*128+kb*32+q*8+j][g*256+ubase+n15]
  short8 wreg[16];
  {
    const int col = g * 256 + ubase + n15;
    #pragma unroll
    for (int m = 0; m < 4; m++) {
      #pragma unroll
      for (int kb = 0; kb < 4; kb++) {
        short8 t;
        #pragma unroll
        for (int j = 0; j < 8; j++)
          t[j] = (short)f2bf(mats[m][(size_t)(kh * 128 + kb * 32 + q * 8 + j) * NG + col]);
        wreg[m * 4 + kb] = t;
      }
    }
  }

  // ---- mask table (LDS): mskl[row][s] for this dir
  for (int i = tid; i < 64 * 256; i += 512) {
    int row = i >> 8, s = i & 255;
    mskl[i] = (s < TM) ? (seqs[row * TT + (dir ? TM - s : s)] != 0) : 0;
  }

  float bi[4];
  {
    const float* bp = tlay ? (b0p + NG) : b0p;
    #pragma unroll
    for (int gg = 0; gg < 4; gg++) bi[gg] = bp[(gg << 8) + ubase + cn];
  }
  float cst = 0.f, hv = 0.f;

  __syncthreads();

  const int wsw = (tid * 16) ^ (((tid >> 5) & 7) << 4);
  const int fb = n15 * 512 + kh * 256;
  const int fx = (n15 & 7) << 4;
  const int zwr = (g << 9) + (kh << 8) + n15;

  // ring word slot: [lay][parity][cluster][4096]
  unsigned int* hst = Hbuf + ((size_t)(tlay * 16 + cluster)) * 4096 + crow * 256 + ubase + cn;
  // dummy-pending scratch (ledger balancing for tlay1's first tick)
  float* dump = (float*)((char*)Hbuf + 524288) + (blk * 512 + tid);

  // deferred out-store state
  const float* pendA = dump;
  float pendV = 0.f;
  bool havePend = false;

  short8 ea[4];  // emb A-frags for the CURRENT tick (prefetched previous tick)

  // ================= tick 0: emb-only, L0 combine =================
  {
    int tx = dir ? TM : 0;
    const unsigned short* ep =
        embb + ((size_t)((rg * 16 + n15) * TT + tx)) * NU + kh * 128 + q * 8;
    f32x4 acc0 = {0.f, 0.f, 0.f, 0.f};
    #pragma unroll
    for (int kb = 0; kb < 4; kb++) {
      short8 a = *(const short8*)(ep + kb * 32);
      acc0 = __builtin_amdgcn_mfma_f32_16x16x32_bf16(a, wreg[kb], acc0, 0, 0, 0);
    }
    #pragma unroll
    for (int j = 0; j < 4; j++) zpart[zwr + (((q << 2) + j) << 4)] = acc0[j];
    LGKM0(); SCHEDBAR(); BAR();
    if (tlay == 0) {
      float z[4];
      #pragma unroll
      for (int gg = 0; gg < 4; gg++)
        z[gg] = zpart[(gg * 2) * 256 + crow * 16 + cn] +
                zpart[(gg * 2 + 1) * 256 + crow * 16 + cn] + bi[gg];
      float cnw = sigm(z[1]) * cst + sigm(z[0]) * tanhp(z[2]);
      float hnw = sigm(z[3]) * tanhp(cnw);
      if (mskl[brow * 256 + 0]) { cst = cnw; hv = hnw; }
      int tout = dir ? TM - 1 : 0;
      pendA = out + (((size_t)((1 + dir * 3) * BB + brow)) * TM + tout) * NU + ubase + cn;
      pendV = hv;
    }
    havePend = true;  // tlay1: dummy (dump) — balances the vmcnt ledger
    // emb prefetch for tick 1 (MUST precede ring store: tick-start VMCNT(1))
    {
      int tx1 = dir ? TM - 1 : 1;
      const unsigned short* e1 =
          embb + ((size_t)((rg * 16 + n15) * TT + tx1)) * NU + kh * 128 + q * 8;
      #pragma unroll
      for (int kb = 0; kb < 4; kb++) CACH_LOAD16(ea[kb], e1 + kb * 32);
    }
    SCHEDBAR();
    // ring store: tlay0 real h0 (tag1,par0); tlay1 h1=0 (tag1,par0 — dead slot,
    // nobody reads h1 at tick1; next write is tag3,par0 read at tick3)
    __hip_atomic_store(hst, (1u << 16) | (unsigned)f2bf(hv),
                       __ATOMIC_RELAXED, __HIP_MEMORY_SCOPE_AGENT);
  }

  // ================= ticks 1..255 =================
  for (int tau = 1; tau < 256; ++tau) {
    const bool doL0 = (tau < TM);
    const bool doH1 = (tau >= 2);
    const int step = tlay ? tau - 1 : tau;

    // tick start: drain the 4 ea prefetch loads (oldest); ring store may pend
    VMCNT(1); SCHEDBAR();

    // pre-poll emb MFMAs (pure reg: ea x wreg)
    f32x4 acc0 = {0.f, 0.f, 0.f, 0.f}, acc1 = {0.f, 0.f, 0.f, 0.f};
    if (doL0) {
      #pragma unroll
      for (int kb = 0; kb < 4; kb++)
        acc0 = __builtin_amdgcn_mfma_f32_16x16x32_bf16(ea[kb], wreg[kb], acc0, 0, 0, 0);
      SCHEDBAR();
    }

    // ---- poll tagged h words; deferred out-store rides as youngest op
    const unsigned tg = (unsigned)tau;
    const int p = (tau + 1) & 1;
    const unsigned int* c0a = Hbuf + ((size_t)(p * 8 + cluster)) * 4096 + tid * 8;
    const unsigned int* c0b = c0a + 4;
    const unsigned int* c1a = Hbuf + ((size_t)((2 + p) * 8 + cluster)) * 4096 + tid * 8;
    const unsigned int* c1b = c1a + 4;
    u32x4 a0 = {0, 0, 0, 0}, a1 = {0, 0, 0, 0}, b0v = {0, 0, 0, 0}, b1v = {0, 0, 0, 0};
    bool first = true;
    int miss = 0;
    for (;;) {
      LLC_LOAD16(a0, c0a);
      LLC_LOAD16(a1, c0b);
      if (doH1) { LLC_LOAD16(b0v, c1a); LLC_LOAD16(b1v, c1b); }
      if (first) {
        if (havePend) { STORE4(pendA, pendV); havePend = false; }
        first = false;
      }
      VMCNT(1); SCHEDBAR();
      bool ok = (a0[0] >> 16) == tg && (a0[1] >> 16) == tg && (a0[2] >> 16) == tg &&
                (a0[3] >> 16) == tg && (a1[0] >> 16) == tg && (a1[1] >> 16) == tg &&
                (a1[2] >> 16) == tg && (a1[3] >> 16) == tg;
      if (doH1)
        ok = ok && (b0v[0] >> 16) == tg && (b0v[1] >> 16) == tg && (b0v[2] >> 16) == tg &&
             (b0v[3] >> 16) == tg && (b1v[0] >> 16) == tg && (b1v[1] >> 16) == tg &&
             (b1v[2] >> 16) == tg && (b1v[3] >> 16) == tg;
      if (__all(ok)) break;
      if (++miss > 2) __builtin_amdgcn_s_sleep(1);
    }
    // strip tags -> packed bf16, stage to swizzled LDS
    u32x4 s0, s1;
    s0[0] = (a0[0] & 0xFFFFu) | (a0[1] << 16);
    s0[1] = (a0[2] & 0xFFFFu) | (a0[3] << 16);
    s0[2] = (a1[0] & 0xFFFFu) | (a1[1] << 16);
    s0[3] = (a1[2] & 0xFFFFu) | (a1[3] << 16);
    *(u32x4*)(hlb0 + wsw) = s0;
    if (doH1) {
      s1[0] = (b0v[0] & 0xFFFFu) | (b0v[1] << 16);
      s1[1] = (b0v[2] & 0xFFFFu) | (b0v[3] << 16);
      s1[2] = (b1v[0] & 0xFFFFu) | (b1v[1] << 16);
      s1[3] = (b1v[2] & 0xFFFFu) | (b1v[3] << 16);
      *(u32x4*)(hlb1 + wsw) = s1;
    }
    LGKM0(); SCHEDBAR(); BAR();

    // ---- h MFMAs (A from LDS, B from wreg)
    #pragma unroll
    for (int kb = 0; kb < 4; kb++) {
      short8 h0f = *(const short8*)(hlb0 + ((fb + kb * 64 + q * 16) ^ fx));
      if (doL0) acc0 = __builtin_amdgcn_mfma_f32_16x16x32_bf16(h0f, wreg[4 + kb], acc0, 0, 0, 0);
      acc1 = __builtin_amdgcn_mfma_f32_16x16x32_bf16(h0f, wreg[8 + kb], acc1, 0, 0, 0);
    }
    if (doH1) {
      #pragma unroll
      for (int kb = 0; kb < 4; kb++) {
        short8 h1f = *(const short8*)(hlb1 + ((fb + kb * 64 + q * 16) ^ fx));
        acc1 = __builtin_amdgcn_mfma_f32_16x16x32_bf16(h1f, wreg[12 + kb], acc1, 0, 0, 0);
      }
    }

    // ---- z partials
    if (doL0) {
      #pragma unroll
      for (int j = 0; j < 4; j++) zpart[zwr + (((q << 2) + j) << 4)] = acc0[j];
    }
    #pragma unroll
    for (int j = 0; j < 4; j++) zpart[2048 + zwr + (((q << 2) + j) << 4)] = acc1[j];
    LGKM0(); SCHEDBAR(); BAR();

    // ---- emb prefetch for tick tau+1 (before ring store; all threads)
    if (tau < TM - 1) {
      int tx1 = dir ? TM - (tau + 1) : (tau + 1);
      const unsigned short* e1 =
          embb + ((size_t)((rg * 16 + n15) * TT + tx1)) * NU + kh * 128 + q * 8;
      #pragma unroll
      for (int kb = 0; kb < 4; kb++) CACH_LOAD16(ea[kb], e1 + kb * 32);
    }
    SCHEDBAR();

    // ---- combine (L0: threads 0-255 @ step tau; L1: threads 256-511 @ tau-1)
    if (tlay ? true : doL0) {
      float z[4];
      #pragma unroll
      for (int gg = 0; gg < 4; gg++)
        z[gg] = zpart[(tlay * 8 + gg * 2) * 256 + crow * 16 + cn] +
                zpart[(tlay * 8 + gg * 2 + 1) * 256 + crow * 16 + cn] + bi[gg];
      float cnw = sigm(z[1]) * cst + sigm(z[0]) * tanhp(z[2]);
      float hnw = sigm(z[3]) * tanhp(cnw);
      if (mskl[brow * 256 + step]) { cst = cnw; hv = hnw; }
      // ring store: tag tau+1, parity tau&1, fire-and-forget sc1
      __hip_atomic_store(hst + (size_t)(tau & 1) * 32768,
                         ((unsigned)(tau + 1) << 16) | (unsigned)f2bf(hv),
                         __ATOMIC_RELAXED, __HIP_MEMORY_SCOPE_AGENT);
      // defer the fp32 out store to next tick's poll
      int tout = dir ? TM - 1 - step : step;
      pendA = out + (((size_t)((1 + tlay + dir * 3) * BB + brow)) * TM + tout) * NU + ubase + cn;
      pendV = hv;
      havePend = true;
    }
  }

  // flush the last deferred store (tlay1's step 254)
  if (havePend) STORE4(pendA, pendV);
}

extern "C" void kernel_launch(void* const* d_in, const int* in_sizes, int n_in,
                              void* d_out, int out_size, void* d_ws, size_t ws_size,
                              hipStream_t stream) {
  const int* seqs = (const int*)d_in[0];
  const float* E = (const float*)d_in[1];
  const float* Wf = (const float*)d_in[2];
  const float* Uf = (const float*)d_in[3];
  const float* bfp = (const float*)d_in[4];
  const float* Wb = (const float*)d_in[5];
  const float* Ub = (const float*)d_in[6];
  const float* bbp = (const float*)d_in[7];
  float* out = (float*)d_out;

  char* ws = (char*)d_ws;
  unsigned int* Hbuf = (unsigned int*)ws;                 // 512KB ring + 256KB dump
  unsigned short* embb = (unsigned short*)(ws + 1048576); // 8MB bf16 emb

  hipMemsetAsync(Hbuf, 0, 4 * 8 * 4096 * sizeof(unsigned int), stream);

  hipLaunchKernelGGL(embed_kernel, dim3(BB, TT), dim3(256), 0, stream,
                     seqs, E, embb, out);

  int smem = 49152;  // 16K zpart + 2x8K h tiles + 16K mask
  hipFuncSetAttribute(reinterpret_cast<const void*>(lstm_kernel),
                      hipFuncAttributeMaxDynamicSharedMemorySize, smem);
  hipLaunchKernelGGL(lstm_kernel, dim3(128), dim3(512), smem, stream,
                     seqs, Wf, Uf, bfp, Wb, Ub, bbp, embb, Hbuf, out);
}